// Round 11
// baseline (320.518 us; speedup 1.0000x reference)
//
#include <hip/hip_runtime.h>
#include <hip/hip_bf16.h>

// ArcFace fused: cos = emb @ (w/||w||), margin at target label, softmax over batch axis.
// N=512, D=512, C=100000, S=1.
//
// ROUND 11 theory: all prior structures shared NBLK*512KB of A-fragment re-reads
// (1.6 GB L2 at BC=32) -> ~8.2 MB/CU through the CU vector-return path, the real
// ~2 TB/s wall. Lever: BC 32->128 cuts per-column bytes 21KB->9KB (A amortized
// over 4x the columns).
//   prep_afrag : emb f32 -> bf16 A-fragments (512 KB, L2-resident)
//   wt_kernel  : w f32 -> bf16 B-fragments + rsqrt col norms (5.5 TB/s measured);
//                grid 3128 (padded cols zero-filled)
//   arcface_main: BC=128, 1024 thr (16 waves), wave = 32 rows x 128 cols,
//                acc[2][8]=64 AGPR, launch_bounds(1024,4). Barrier-free K-loop,
//                compiler-scheduled (hand rings falsified r10). tgt one-hot scan
//                fused. Fixed-shift softmax epilogue (validated r9).

static constexpr int DIM    = 512;
static constexpr int NROWS  = 512;
static constexpr int NCLS   = 100000;
static constexpr int BC     = 128;             // columns per block (main)
static constexpr int BK     = 32;              // K per step
static constexpr int NSTEP  = DIM / BK;        // 16
static constexpr int MT     = NROWS / 16;      // 32
static constexpr int NBLK   = (NCLS + BC - 1) / BC;   // 782 (last block guarded)
static constexpr int WTBLK  = NBLK * 4;        // 3128 32-col groups (padded)

static constexpr float COS_M = 0.87758256189037271611f;  // cos(0.5)
static constexpr float SIN_M = 0.47942553860420300027f;  // sin(0.5)
static constexpr float SCALE = 64.0f;
static constexpr float SHIFT = 20.0f;          // fixed softmax shift

typedef __attribute__((ext_vector_type(8))) short bf16x8;
typedef __attribute__((ext_vector_type(4))) float f32x4;

#define MFMA16(A, B, C) __builtin_amdgcn_mfma_f32_16x16x32_bf16((A), (B), (C), 0, 0, 0)

__device__ __forceinline__ unsigned short f2bf(float f) {
  union { float f; unsigned u; } v; v.f = f;
  unsigned u = v.u;
  return (unsigned short)((u + 0x7FFFu + ((u >> 16) & 1u)) >> 16);
}

// ---------------------------------------------------------------------------
__global__ void prep_afrag(const float* __restrict__ emb,
                           unsigned short* __restrict__ afrag) {
  const int idx = blockIdx.x * blockDim.x + threadIdx.x;  // 0..32767
  const int l  = idx & 63;
  const int mt = (idx >> 6) & 31;
  const int ks = idx >> 11;
  const int row = mt * 16 + (l & 15);
  const int k0  = ks * 32 + (l >> 4) * 8;

  unsigned short t[8];
#pragma unroll
  for (int j = 0; j < 8; ++j) t[j] = f2bf(emb[row * DIM + k0 + j]);

  uint4 v;
  v.x = (unsigned)t[0] | ((unsigned)t[1] << 16);
  v.y = (unsigned)t[2] | ((unsigned)t[3] << 16);
  v.z = (unsigned)t[4] | ((unsigned)t[5] << 16);
  v.w = (unsigned)t[6] | ((unsigned)t[7] << 16);
  *reinterpret_cast<uint4*>(&afrag[(size_t)idx * 8]) = v;
}

// ---------------------------------------------------------------------------
// wt_kernel: 32-col group cb (0..3127; cols >= NCLS zero-filled).
// bfrag[((cb*16 + ks)*2 + j)*512 + l2*8 + e] = bf16 fragment; rnorm padded.
// ---------------------------------------------------------------------------
__global__ __launch_bounds__(256)
void wt_kernel(const float* __restrict__ w,
               unsigned short* __restrict__ bfrag,
               float* __restrict__ rnorm) {
  __shared__ float S[32][33];
  __shared__ float NRM[32][32];

  const int t  = threadIdx.x;
  const int cb = blockIdx.x;
  const int c0 = cb * 32;

  const int rk = t >> 3;
  const int rc = (t & 7) * 4;
  const bool ok4 = (c0 + rc + 3) < NCLS;

  float4 nrm4 = {0.f, 0.f, 0.f, 0.f};

  for (int p = 0; p < NSTEP; ++p) {
    float4 v = {0.f, 0.f, 0.f, 0.f};
    const size_t rb = (size_t)(p * BK + rk) * NCLS;
    if (ok4) {
      v = *reinterpret_cast<const float4*>(w + rb + c0 + rc);
    } else {
      if (c0 + rc + 0 < NCLS) v.x = w[rb + c0 + rc + 0];
      if (c0 + rc + 1 < NCLS) v.y = w[rb + c0 + rc + 1];
      if (c0 + rc + 2 < NCLS) v.z = w[rb + c0 + rc + 2];
      if (c0 + rc + 3 < NCLS) v.w = w[rb + c0 + rc + 3];
    }
    nrm4.x += v.x * v.x; nrm4.y += v.y * v.y;
    nrm4.z += v.z * v.z; nrm4.w += v.w * v.w;
    __syncthreads();
    *reinterpret_cast<float4*>(&S[rk][rc]) = v;
    __syncthreads();

    if (t < 128) {
      const int l2 = t & 63;
      const int j  = t >> 6;
      const int col = j * 16 + (l2 & 15);
      const int kb  = (l2 >> 4) * 8;
      uint4 pk;
      pk.x = (unsigned)f2bf(S[kb + 0][col]) | ((unsigned)f2bf(S[kb + 1][col]) << 16);
      pk.y = (unsigned)f2bf(S[kb + 2][col]) | ((unsigned)f2bf(S[kb + 3][col]) << 16);
      pk.z = (unsigned)f2bf(S[kb + 4][col]) | ((unsigned)f2bf(S[kb + 5][col]) << 16);
      pk.w = (unsigned)f2bf(S[kb + 6][col]) | ((unsigned)f2bf(S[kb + 7][col]) << 16);
      *reinterpret_cast<uint4*>(
          &bfrag[(((size_t)(cb * NSTEP + p) * 2 + j) * 64 + l2) * 8]) = pk;
    }
  }

  NRM[rk][rc + 0] = nrm4.x;
  NRM[rk][rc + 1] = nrm4.y;
  NRM[rk][rc + 2] = nrm4.z;
  NRM[rk][rc + 3] = nrm4.w;
  __syncthreads();
  if (t < 32) {
    float s = 0.f;
#pragma unroll
    for (int g = 0; g < 32; ++g) s += NRM[g][t];
    rnorm[c0 + t] = rsqrtf(fmaxf(s, 1e-20f));
  }
}

// ---------------------------------------------------------------------------
// Main kernel. 1024 threads = 16 waves, 1 block/CU. Wave wv owns rows
// [wv*32, wv*32+32) x all 128 block columns. Barrier-free K-loop.
// ---------------------------------------------------------------------------
__global__ __launch_bounds__(1024, 4)
void arcface_main(const unsigned short* __restrict__ bfrag,
                  const unsigned short* __restrict__ afrag,
                  const float* __restrict__ rnorm,
                  const float* __restrict__ tgt,
                  float* __restrict__ out) {
  __shared__ float red[16][BC];
  __shared__ float colv[BC];
  __shared__ unsigned char labL[NROWS];

  const int tid = threadIdx.x;
  const int wv  = tid >> 6;        // 0..15
  const int l   = tid & 63;
  const int lh  = l >> 4;
  const int ll  = l & 15;
  const int c0  = blockIdx.x * BC;

  if (tid < 128) reinterpret_cast<unsigned*>(labL)[tid] = 0u;
  __syncthreads();

  // tgt scan role: thread covers rows (tid>>5)*16 + ks, cols c0 + (tid&31)*4
  const int trg = tid >> 5;            // 0..31
  const int tcc = (tid & 31) * 4;      // 0..124
  const bool tok = (c0 + tcc + 3) < NCLS;   // last block: cols >=32 invalid
  const float* tgtp = tgt + (size_t)(trg * 16) * NCLS + c0 + tcc;

  const unsigned short* pA = afrag + ((size_t)(wv * 2) * 64 + l) * 8;
  const unsigned short* pB = bfrag + (size_t)blockIdx.x * 65536 + (size_t)l * 8;

  f32x4 acc[2][8] = {};

#pragma unroll
  for (int ks = 0; ks < NSTEP; ++ks) {
    // tgt one-hot scan (zero-filled OOB -> no labL writes)
    {
      float4 tv = {0.f, 0.f, 0.f, 0.f};
      if (tok) tv = *reinterpret_cast<const float4*>(tgtp + (size_t)ks * NCLS);
      const int trow = trg * 16 + ks;
      if (tv.x > 0.5f) labL[trow] = (unsigned char)(tcc + 1);
      if (tv.y > 0.5f) labL[trow] = (unsigned char)(tcc + 2);
      if (tv.z > 0.5f) labL[trow] = (unsigned char)(tcc + 3);
      if (tv.w > 0.5f) labL[trow] = (unsigned char)(tcc + 4);
    }

    bf16x8 a0 = *reinterpret_cast<const bf16x8*>(pA + (size_t)(ks * MT + 0) * 512);
    bf16x8 a1 = *reinterpret_cast<const bf16x8*>(pA + (size_t)(ks * MT + 1) * 512);

    // first 4 N-tiles
    bf16x8 b;
#pragma unroll
    for (int jj = 0; jj < 4; ++jj) {
      b = *reinterpret_cast<const bf16x8*>(
          pB + (size_t)(jj >> 1) * 16384 + (size_t)ks * 1024 + (size_t)(jj & 1) * 512);
      acc[0][jj] = MFMA16(a0, b, acc[0][jj]);
      acc[1][jj] = MFMA16(a1, b, acc[1][jj]);
    }
    // last 4 N-tiles
#pragma unroll
    for (int jj = 4; jj < 8; ++jj) {
      b = *reinterpret_cast<const bf16x8*>(
          pB + (size_t)(jj >> 1) * 16384 + (size_t)ks * 1024 + (size_t)(jj & 1) * 512);
      acc[0][jj] = MFMA16(a0, b, acc[0][jj]);
      acc[1][jj] = MFMA16(a1, b, acc[1][jj]);
    }
  }

  // ---- epilogue (fixed-shift softmax)
  __syncthreads();   // labL visibility

  int lab[2][4];
#pragma unroll
  for (int i = 0; i < 2; ++i)
#pragma unroll
    for (int q = 0; q < 4; ++q)
      lab[i][q] = (int)labL[wv * 32 + i * 16 + lh * 4 + q] - 1;  // local col or -1

  float sme[8];
#pragma unroll
  for (int jj = 0; jj < 8; ++jj) {
    const int jl = jj * 16 + ll;
    const float rn = rnorm[c0 + jl];
    float s8 = 0.f;
#pragma unroll
    for (int i = 0; i < 2; ++i) {
#pragma unroll
      for (int q = 0; q < 4; ++q) {
        float cosv = acc[i][jj][q] * rn;
        cosv = fminf(fmaxf(cosv, -1.f), 1.f);
        float lg;
        if (lab[i][q] == jl) {
          const float s = sqrtf(fmaxf(1.f - cosv * cosv, 0.f));
          lg = cosv * COS_M - s * SIN_M;
        } else {
          lg = cosv;
        }
        const float e = __expf(lg * SCALE - SHIFT);
        acc[i][jj][q] = e;
        s8 += e;
      }
    }
    sme[jj] = s8;
  }

  // column sums: within wave (rows differ by lh -> xor 16/32), then 16 waves via LDS
#pragma unroll
  for (int jj = 0; jj < 8; ++jj) {
    sme[jj] += __shfl_xor(sme[jj], 16, 64);
    sme[jj] += __shfl_xor(sme[jj], 32, 64);
  }
  if (l < 16) {
#pragma unroll
    for (int jj = 0; jj < 8; ++jj) red[wv][jj * 16 + l] = sme[jj];
  }
  __syncthreads();
  if (tid < BC) {
    float s = 0.f;
#pragma unroll
    for (int v2 = 0; v2 < 16; ++v2) s += red[v2][tid];
    colv[tid] = s;
  }
  __syncthreads();

#pragma unroll
  for (int jj = 0; jj < 8; ++jj) {
    const int cj = c0 + jj * 16 + ll;
    if (cj >= NCLS) continue;
    const float rs = 1.0f / colv[jj * 16 + ll];
#pragma unroll
    for (int i = 0; i < 2; ++i) {
#pragma unroll
      for (int q = 0; q < 4; ++q) {
        const int row = wv * 32 + i * 16 + lh * 4 + q;
        out[(size_t)row * NCLS + cj] = acc[i][jj][q] * rs;
      }
    }
  }
}

extern "C" void kernel_launch(void* const* d_in, const int* in_sizes, int n_in,
                              void* d_out, int out_size, void* d_ws, size_t ws_size,
                              hipStream_t stream) {
  const float* emb = (const float*)d_in[0];   // [512][512]
  const float* w   = (const float*)d_in[1];   // [512][100000]
  const float* tgt = (const float*)d_in[2];   // [512][100000]
  float* out = (float*)d_out;                 // [512][100000]

  char* ws = (char*)d_ws;
  unsigned short* afrag = (unsigned short*)(ws + 4096);          // 512 KB
  float* rnorm          = (float*)(ws + (1u << 20));             // 400.4 KB (padded)
  unsigned short* bfrag = (unsigned short*)(ws + (2u << 20));    // 102.4 MB (padded)

  prep_afrag<<<64, 512, 0, stream>>>(emb, afrag);
  wt_kernel<<<WTBLK, 256, 0, stream>>>(w, bfrag, rnorm);
  arcface_main<<<NBLK, 1024, 0, stream>>>(bfrag, afrag, rnorm, tgt, out);
}

// Round 12
// 276.907 us; speedup vs baseline: 1.1575x; 1.1575x over previous
//
#include <hip/hip_runtime.h>
#include <hip/hip_bf16.h>

// ArcFace fused: cos = emb @ (w/||w||), margin at target label, softmax over batch axis.
// N=512, D=512, C=100000 (= 3125*32 exact), S=1.
//
// ROUND 12 theory: vmcnt is an in-order FIFO -- consuming ANY load forces all older
// outstanding loads to return. Every kernel since r3 mixed fast (afrag/L2) and slow
// (bfrag/tgt HBM) loads in one per-wave queue, so each step's MFMA wait drained the
// deep prefetches => serial memory latency per step regardless of structure. Fix =
// the m97 canonical GEMM anatomy: BOTH operands staged through LDS by global_load_lds
// (single uniform vmcnt stream, counted waits, never drained mid-loop); consumption
// via ds_read/lgkmcnt (separate counter). No VGPR global loads inside the K-loop.
//
//   label_scan : tgt one-hot -> labels[512] (global col ids)
//   prep_afrag : emb f32 -> bf16 A-fragments (512 KB, L2-resident)
//   wt_kernel  : w f32 -> bf16 B-fragments + rsqrt col norms (5.6 TB/s measured)
//   arcface_main: BC=32, 512 thr, 2 blocks/CU. Per step: gl_lds stage A(32KB)+B(2KB)
//                into LDS dbuf, depth-1; 2 raw barriers; vmcnt(4/5) counted (0 only at
//                last step); ds_read_b128 fragments; 8 MFMA. Fixed-shift epilogue.

static constexpr int DIM    = 512;
static constexpr int NROWS  = 512;
static constexpr int NCLS   = 100000;
static constexpr int BC     = 32;
static constexpr int BK     = 32;
static constexpr int NSTEP  = DIM / BK;        // 16
static constexpr int MT     = NROWS / 16;      // 32
static constexpr int NBLK   = NCLS / BC;       // 3125

static constexpr float COS_M = 0.87758256189037271611f;  // cos(0.5)
static constexpr float SIN_M = 0.47942553860420300027f;  // sin(0.5)
static constexpr float SCALE = 64.0f;
static constexpr float SHIFT = 20.0f;

typedef __attribute__((ext_vector_type(8))) short bf16x8;
typedef __attribute__((ext_vector_type(4))) float f32x4;

#define MFMA16(A, B, C) __builtin_amdgcn_mfma_f32_16x16x32_bf16((A), (B), (C), 0, 0, 0)

__device__ __forceinline__ unsigned short f2bf(float f) {
  union { float f; unsigned u; } v; v.f = f;
  unsigned u = v.u;
  return (unsigned short)((u + 0x7FFFu + ((u >> 16) & 1u)) >> 16);
}

// ---------------------------------------------------------------------------
__global__ __launch_bounds__(1024)
void label_scan(const float* __restrict__ tgt, int* __restrict__ labels) {
  const int row = blockIdx.x;
  const int nq = NCLS / 4;
  const int q0 = blockIdx.y * (nq / 4);
  const int q1 = (blockIdx.y == 3) ? nq : q0 + (nq / 4);
  const float4* rp = reinterpret_cast<const float4*>(tgt + (size_t)row * NCLS);
  int found = -1;
  for (int c4 = q0 + threadIdx.x; c4 < q1; c4 += 1024) {
    const float4 v = rp[c4];
    if (v.x > 0.5f) found = c4 * 4 + 0;
    if (v.y > 0.5f) found = c4 * 4 + 1;
    if (v.z > 0.5f) found = c4 * 4 + 2;
    if (v.w > 0.5f) found = c4 * 4 + 3;
  }
  if (found >= 0) labels[row] = found;   // exactly one writer per row
}

// ---------------------------------------------------------------------------
__global__ void prep_afrag(const float* __restrict__ emb,
                           unsigned short* __restrict__ afrag) {
  const int idx = blockIdx.x * blockDim.x + threadIdx.x;  // 0..32767
  const int l  = idx & 63;
  const int mt = (idx >> 6) & 31;
  const int ks = idx >> 11;
  const int row = mt * 16 + (l & 15);
  const int k0  = ks * 32 + (l >> 4) * 8;

  unsigned short t[8];
#pragma unroll
  for (int j = 0; j < 8; ++j) t[j] = f2bf(emb[row * DIM + k0 + j]);

  uint4 v;
  v.x = (unsigned)t[0] | ((unsigned)t[1] << 16);
  v.y = (unsigned)t[2] | ((unsigned)t[3] << 16);
  v.z = (unsigned)t[4] | ((unsigned)t[5] << 16);
  v.w = (unsigned)t[6] | ((unsigned)t[7] << 16);
  *reinterpret_cast<uint4*>(&afrag[(size_t)idx * 8]) = v;
}

// ---------------------------------------------------------------------------
__global__ __launch_bounds__(256)
void wt_kernel(const float* __restrict__ w,
               unsigned short* __restrict__ bfrag,
               float* __restrict__ rnorm) {
  __shared__ float S[32][33];
  __shared__ float NRM[32][32];

  const int t  = threadIdx.x;
  const int cb = blockIdx.x;
  const int c0 = cb * 32;

  const int rk = t >> 3;
  const int rc = (t & 7) * 4;

  float4 nrm4 = {0.f, 0.f, 0.f, 0.f};

  for (int p = 0; p < NSTEP; ++p) {
    const float4 v = *reinterpret_cast<const float4*>(
        w + (size_t)(p * BK + rk) * NCLS + c0 + rc);
    nrm4.x += v.x * v.x; nrm4.y += v.y * v.y;
    nrm4.z += v.z * v.z; nrm4.w += v.w * v.w;
    __syncthreads();
    *reinterpret_cast<float4*>(&S[rk][rc]) = v;
    __syncthreads();

    if (t < 128) {
      const int l2 = t & 63;
      const int j  = t >> 6;
      const int col = j * 16 + (l2 & 15);
      const int kb  = (l2 >> 4) * 8;
      uint4 pk;
      pk.x = (unsigned)f2bf(S[kb + 0][col]) | ((unsigned)f2bf(S[kb + 1][col]) << 16);
      pk.y = (unsigned)f2bf(S[kb + 2][col]) | ((unsigned)f2bf(S[kb + 3][col]) << 16);
      pk.z = (unsigned)f2bf(S[kb + 4][col]) | ((unsigned)f2bf(S[kb + 5][col]) << 16);
      pk.w = (unsigned)f2bf(S[kb + 6][col]) | ((unsigned)f2bf(S[kb + 7][col]) << 16);
      *reinterpret_cast<uint4*>(
          &bfrag[(((size_t)(cb * NSTEP + p) * 2 + j) * 64 + l2) * 8]) = pk;
    }
  }

  NRM[rk][rc + 0] = nrm4.x;
  NRM[rk][rc + 1] = nrm4.y;
  NRM[rk][rc + 2] = nrm4.z;
  NRM[rk][rc + 3] = nrm4.w;
  __syncthreads();
  if (t < 32) {
    float s = 0.f;
#pragma unroll
    for (int g = 0; g < 32; ++g) s += NRM[g][t];
    rnorm[c0 + t] = rsqrtf(fmaxf(s, 1e-20f));
  }
}

// ---------------------------------------------------------------------------
// Main kernel. 512 threads = 8 waves, 2 blocks/CU.
// Wave wv owns rows [wv*64, wv*64+64) x the block's 32 columns.
// ---------------------------------------------------------------------------
__global__ __launch_bounds__(512, 4)
void arcface_main(const unsigned short* __restrict__ bfrag,
                  const unsigned short* __restrict__ afrag,
                  const float* __restrict__ rnorm,
                  const int* __restrict__ labels,
                  float* __restrict__ out) {
  __shared__ alignas(16) unsigned short A2[2][16384];  // 2 x 32 KB A step-slices
  __shared__ alignas(16) unsigned short B2[2][1024];   // 2 x 2 KB B step-frags
  __shared__ float red[8][BC];
  __shared__ float colv[BC];

  const int tid = threadIdx.x;
  const int wv  = tid >> 6;
  const int l   = tid & 63;
  const int lh  = l >> 4;
  const int ll  = l & 15;
  const int c0  = blockIdx.x * BC;

  const char* afb = (const char*)afrag;
  const char* bfb = (const char*)bfrag + (size_t)blockIdx.x * 32768;

  // stage tile KS into buffer BUF: 4 A-chunks per wave + 1 B-chunk for waves 0,1.
  // gl_lds: LDS dest = wave-uniform base (+ lane*16 by HW); global src per-lane.
#define STAGE(KS, BUF)                                                          \
  {                                                                             \
    _Pragma("unroll")                                                           \
    for (int j = 0; j < 4; ++j) {                                               \
      const int dof = __builtin_amdgcn_readfirstlane(wv * 4096 + j * 1024);     \
      __builtin_amdgcn_global_load_lds(                                         \
          (const __attribute__((address_space(1))) void*)                      \
              (afb + (size_t)(KS) * 32768 + wv * 4096 + j * 1024 + l * 16),     \
          (__attribute__((address_space(3))) void*)((char*)&A2[BUF][0] + dof),  \
          16, 0, 0);                                                            \
    }                                                                           \
    if (wv < 2) {                                                               \
      const int dofb = __builtin_amdgcn_readfirstlane(wv * 1024);               \
      __builtin_amdgcn_global_load_lds(                                         \
          (const __attribute__((address_space(1))) void*)                      \
              (bfb + (size_t)(KS) * 2048 + wv * 1024 + l * 16),                 \
          (__attribute__((address_space(3))) void*)((char*)&B2[BUF][0] + dofb), \
          16, 0, 0);                                                            \
    }                                                                           \
  }

  f32x4 acc[4][2] = {};

  // prologue: stage tiles 0 and 1 (per-wave queue: A0 x4, [B0], A1 x4, [B1])
  STAGE(0, 0)
  STAGE(1, 1)

  // per-step: counted vmcnt (tile K landed; K+1 still in flight) -> barrier ->
  // ds_read frags -> lgkmcnt(0) -> barrier (buffer free) -> stage K+2 -> MFMA.
#define STEP(KS, VMA, VMB)                                                      \
  {                                                                             \
    if (wv < 2) { asm volatile("s_waitcnt vmcnt(" #VMB ")" ::: "memory"); }     \
    else        { asm volatile("s_waitcnt vmcnt(" #VMA ")" ::: "memory"); }     \
    __builtin_amdgcn_s_barrier();                                               \
    __builtin_amdgcn_sched_barrier(0);                                          \
    bf16x8 a0 = *reinterpret_cast<const bf16x8*>(&A2[(KS) & 1][(wv * 4 + 0) * 512 + l * 8]); \
    bf16x8 a1 = *reinterpret_cast<const bf16x8*>(&A2[(KS) & 1][(wv * 4 + 1) * 512 + l * 8]); \
    bf16x8 a2 = *reinterpret_cast<const bf16x8*>(&A2[(KS) & 1][(wv * 4 + 2) * 512 + l * 8]); \
    bf16x8 a3 = *reinterpret_cast<const bf16x8*>(&A2[(KS) & 1][(wv * 4 + 3) * 512 + l * 8]); \
    bf16x8 b0 = *reinterpret_cast<const bf16x8*>(&B2[(KS) & 1][0 * 512 + l * 8]);            \
    bf16x8 b1 = *reinterpret_cast<const bf16x8*>(&B2[(KS) & 1][1 * 512 + l * 8]);            \
    asm volatile("s_waitcnt lgkmcnt(0)" ::: "memory");                          \
    __builtin_amdgcn_sched_barrier(0);                                          \
    __builtin_amdgcn_s_barrier();                                               \
    if ((KS) + 2 < NSTEP) STAGE((KS) + 2, (KS) & 1)                             \
    __builtin_amdgcn_sched_barrier(0);                                          \
    acc[0][0] = MFMA16(a0, b0, acc[0][0]);                                      \
    acc[0][1] = MFMA16(a0, b1, acc[0][1]);                                      \
    acc[1][0] = MFMA16(a1, b0, acc[1][0]);                                      \
    acc[1][1] = MFMA16(a1, b1, acc[1][1]);                                      \
    acc[2][0] = MFMA16(a2, b0, acc[2][0]);                                      \
    acc[2][1] = MFMA16(a2, b1, acc[2][1]);                                      \
    acc[3][0] = MFMA16(a3, b0, acc[3][0]);                                      \
    acc[3][1] = MFMA16(a3, b1, acc[3][1]);                                      \
  }

  STEP(0, 4, 5)   STEP(1, 4, 5)   STEP(2, 4, 5)   STEP(3, 4, 5)
  STEP(4, 4, 5)   STEP(5, 4, 5)   STEP(6, 4, 5)   STEP(7, 4, 5)
  STEP(8, 4, 5)   STEP(9, 4, 5)   STEP(10, 4, 5)  STEP(11, 4, 5)
  STEP(12, 4, 5)  STEP(13, 4, 5)  STEP(14, 4, 5)  STEP(15, 0, 0)
#undef STEP
#undef STAGE

  __syncthreads();
  __builtin_amdgcn_sched_barrier(0);

  // ---- epilogue (fixed-shift softmax; labels are global col ids)
  float rn[2];
#pragma unroll
  for (int j = 0; j < 2; ++j) rn[j] = rnorm[c0 + j * 16 + ll];

  int lab[4][4];
#pragma unroll
  for (int i = 0; i < 4; ++i)
#pragma unroll
    for (int q = 0; q < 4; ++q)
      lab[i][q] = labels[wv * 64 + i * 16 + lh * 4 + q];

  float sme[2] = {0.f, 0.f};
#pragma unroll
  for (int j = 0; j < 2; ++j) {
    const int cj = c0 + j * 16 + ll;
#pragma unroll
    for (int i = 0; i < 4; ++i) {
#pragma unroll
      for (int q = 0; q < 4; ++q) {
        float cosv = acc[i][j][q] * rn[j];
        cosv = fminf(fmaxf(cosv, -1.f), 1.f);
        float lg;
        if (lab[i][q] == cj) {
          const float s = sqrtf(fmaxf(1.f - cosv * cosv, 0.f));
          lg = cosv * COS_M - s * SIN_M;
        } else {
          lg = cosv;
        }
        const float e = __expf(lg * SCALE - SHIFT);
        acc[i][j][q] = e;
        sme[j] += e;
      }
    }
  }

#pragma unroll
  for (int j = 0; j < 2; ++j) {
    sme[j] += __shfl_xor(sme[j], 16, 64);
    sme[j] += __shfl_xor(sme[j], 32, 64);
  }
  if (l < 16) {
#pragma unroll
    for (int j = 0; j < 2; ++j) red[wv][j * 16 + l] = sme[j];
  }
  __syncthreads();
  if (tid < BC) {
    float s = 0.f;
#pragma unroll
    for (int v2 = 0; v2 < 8; ++v2) s += red[v2][tid];
    colv[tid] = s;
  }
  __syncthreads();

  float rs[2];
#pragma unroll
  for (int j = 0; j < 2; ++j) rs[j] = 1.0f / colv[j * 16 + ll];

#pragma unroll
  for (int j = 0; j < 2; ++j) {
    const int cj = c0 + j * 16 + ll;
#pragma unroll
    for (int i = 0; i < 4; ++i) {
#pragma unroll
      for (int q = 0; q < 4; ++q) {
        const int row = wv * 64 + i * 16 + lh * 4 + q;
        out[(size_t)row * NCLS + cj] = acc[i][j][q] * rs[j];
      }
    }
  }
}

extern "C" void kernel_launch(void* const* d_in, const int* in_sizes, int n_in,
                              void* d_out, int out_size, void* d_ws, size_t ws_size,
                              hipStream_t stream) {
  const float* emb = (const float*)d_in[0];   // [512][512]
  const float* w   = (const float*)d_in[1];   // [512][100000]
  const float* tgt = (const float*)d_in[2];   // [512][100000]
  float* out = (float*)d_out;                 // [512][100000]

  char* ws = (char*)d_ws;
  int* labels           = (int*)ws;                              // 2 KB
  unsigned short* afrag = (unsigned short*)(ws + 4096);          // 512 KB
  float* rnorm          = (float*)(ws + (1u << 20));             // 400 KB
  unsigned short* bfrag = (unsigned short*)(ws + (2u << 20));    // 100 MB

  label_scan<<<dim3(NROWS, 4), 1024, 0, stream>>>(tgt, labels);
  prep_afrag<<<64, 512, 0, stream>>>(emb, afrag);
  wt_kernel<<<NBLK, 256, 0, stream>>>(w, bfrag, rnorm);
  arcface_main<<<NBLK, 512, 0, stream>>>(bfrag, afrag, rnorm, labels, out);
}

// Round 13
// 274.426 us; speedup vs baseline: 1.1680x; 1.0090x over previous
//
#include <hip/hip_runtime.h>
#include <hip/hip_bf16.h>

// ArcFace fused: cos = emb @ (w/||w||), margin at target label, softmax over batch axis.
// N=512, D=512, C=100000, S=1.
//
// ROUND 13: r12 validated the vmcnt-FIFO theory (LDS staging + counted waits: 250->169us).
// Remaining cost = the A stream through LDS (64KB of 82KB LDS/step) + A L2 traffic.
// Fix: A fragments load DIRECT to VGPR from L2 (lane-contiguous, 2 dwordx4/wave/step)
// issued BEFORE the B gl_lds stage each step, so the steady wait is vmcnt(1): B(K+1)
// stays in flight, A(K+1) gets 1 step of lead (L2 latency << step). B stays LDS-staged
// (shared by 16 waves). BC=64 halves the A re-read traffic vs BC=32.
//
//   label_scan : tgt one-hot -> labels[512] (global col ids, ~35us BW-bound)
//   prep_afrag : emb f32 -> bf16 A-fragments (512 KB, L2-resident)
//   wt_kernel  : w f32 -> bf16 B-fragments + rsqrt col norms (~55us, 5.5 TB/s);
//                grid 3126, pad group zero-filled
//   arcface_main: 1024 thr = 16 waves, wave = 32 rows x 64 cols, acc[2][4]=32 AGPR.
//                Per step: vmcnt(1) -> barrier -> ds_read B x4 -> load A(K+1) direct
//                -> lgkmcnt(0) -> barrier -> gl_lds stage B(K+2) -> 8 MFMA.
//                Fixed-shift softmax epilogue (validated r9).

static constexpr int DIM    = 512;
static constexpr int NROWS  = 512;
static constexpr int NCLS   = 100000;
static constexpr int BC     = 64;
static constexpr int BK     = 32;
static constexpr int NSTEP  = DIM / BK;        // 16
static constexpr int MT     = NROWS / 16;      // 32
static constexpr int NBLK   = (NCLS + BC - 1) / BC;   // 1563 (last block half-valid)
static constexpr int WTBLK  = NBLK * 2;        // 3126 32-col groups (1 pad group)

static constexpr float COS_M = 0.87758256189037271611f;  // cos(0.5)
static constexpr float SIN_M = 0.47942553860420300027f;  // sin(0.5)
static constexpr float SCALE = 64.0f;
static constexpr float SHIFT = 20.0f;          // fixed softmax shift

typedef __attribute__((ext_vector_type(8))) short bf16x8;
typedef __attribute__((ext_vector_type(4))) float f32x4;

#define MFMA16(A, B, C) __builtin_amdgcn_mfma_f32_16x16x32_bf16((A), (B), (C), 0, 0, 0)

__device__ __forceinline__ unsigned short f2bf(float f) {
  union { float f; unsigned u; } v; v.f = f;
  unsigned u = v.u;
  return (unsigned short)((u + 0x7FFFu + ((u >> 16) & 1u)) >> 16);
}

// ---------------------------------------------------------------------------
__global__ __launch_bounds__(1024)
void label_scan(const float* __restrict__ tgt, int* __restrict__ labels) {
  const int row = blockIdx.x;
  const int nq = NCLS / 4;
  const int q0 = blockIdx.y * (nq / 4);
  const int q1 = (blockIdx.y == 3) ? nq : q0 + (nq / 4);
  const float4* rp = reinterpret_cast<const float4*>(tgt + (size_t)row * NCLS);
  int found = -1;
  for (int c4 = q0 + threadIdx.x; c4 < q1; c4 += 1024) {
    const float4 v = rp[c4];
    if (v.x > 0.5f) found = c4 * 4 + 0;
    if (v.y > 0.5f) found = c4 * 4 + 1;
    if (v.z > 0.5f) found = c4 * 4 + 2;
    if (v.w > 0.5f) found = c4 * 4 + 3;
  }
  if (found >= 0) labels[row] = found;   // exactly one writer per row
}

// ---------------------------------------------------------------------------
__global__ void prep_afrag(const float* __restrict__ emb,
                           unsigned short* __restrict__ afrag) {
  const int idx = blockIdx.x * blockDim.x + threadIdx.x;  // 0..32767
  const int l  = idx & 63;
  const int mt = (idx >> 6) & 31;
  const int ks = idx >> 11;
  const int row = mt * 16 + (l & 15);
  const int k0  = ks * 32 + (l >> 4) * 8;

  unsigned short t[8];
#pragma unroll
  for (int j = 0; j < 8; ++j) t[j] = f2bf(emb[row * DIM + k0 + j]);

  uint4 v;
  v.x = (unsigned)t[0] | ((unsigned)t[1] << 16);
  v.y = (unsigned)t[2] | ((unsigned)t[3] << 16);
  v.z = (unsigned)t[4] | ((unsigned)t[5] << 16);
  v.w = (unsigned)t[6] | ((unsigned)t[7] << 16);
  *reinterpret_cast<uint4*>(&afrag[(size_t)idx * 8]) = v;
}

// ---------------------------------------------------------------------------
// wt_kernel: 32-col group cb (0..3125). cb==3125 is padding: zero-filled.
// bfrag fragment fi = (cb*16 + p)*2 + j  (1 KB each, lane-contiguous).
// ---------------------------------------------------------------------------
__global__ __launch_bounds__(256)
void wt_kernel(const float* __restrict__ w,
               unsigned short* __restrict__ bfrag,
               float* __restrict__ rnorm) {
  __shared__ float S[32][33];
  __shared__ float NRM[32][32];

  const int t  = threadIdx.x;
  const int cb = blockIdx.x;
  const int c0 = cb * 32;
  const bool valid = c0 < NCLS;      // whole 32-col group valid or not (exact split)

  const int rk = t >> 3;
  const int rc = (t & 7) * 4;

  float4 nrm4 = {0.f, 0.f, 0.f, 0.f};

  for (int p = 0; p < NSTEP; ++p) {
    float4 v = {0.f, 0.f, 0.f, 0.f};
    if (valid)
      v = *reinterpret_cast<const float4*>(w + (size_t)(p * BK + rk) * NCLS + c0 + rc);
    nrm4.x += v.x * v.x; nrm4.y += v.y * v.y;
    nrm4.z += v.z * v.z; nrm4.w += v.w * v.w;
    __syncthreads();
    *reinterpret_cast<float4*>(&S[rk][rc]) = v;
    __syncthreads();

    if (t < 128) {
      const int l2 = t & 63;
      const int j  = t >> 6;
      const int col = j * 16 + (l2 & 15);
      const int kb  = (l2 >> 4) * 8;
      uint4 pk;
      pk.x = (unsigned)f2bf(S[kb + 0][col]) | ((unsigned)f2bf(S[kb + 1][col]) << 16);
      pk.y = (unsigned)f2bf(S[kb + 2][col]) | ((unsigned)f2bf(S[kb + 3][col]) << 16);
      pk.z = (unsigned)f2bf(S[kb + 4][col]) | ((unsigned)f2bf(S[kb + 5][col]) << 16);
      pk.w = (unsigned)f2bf(S[kb + 6][col]) | ((unsigned)f2bf(S[kb + 7][col]) << 16);
      *reinterpret_cast<uint4*>(
          &bfrag[(((size_t)(cb * NSTEP + p) * 2 + j) * 64 + l2) * 8]) = pk;
    }
  }

  NRM[rk][rc + 0] = nrm4.x;
  NRM[rk][rc + 1] = nrm4.y;
  NRM[rk][rc + 2] = nrm4.z;
  NRM[rk][rc + 3] = nrm4.w;
  __syncthreads();
  if (t < 32) {
    float s = 0.f;
#pragma unroll
    for (int g = 0; g < 32; ++g) s += NRM[g][t];
    rnorm[c0 + t] = rsqrtf(fmaxf(s, 1e-20f));
  }
}

// ---------------------------------------------------------------------------
// Main kernel. 1024 threads = 16 waves, 1 block/CU (4 waves/SIMD).
// Wave wv owns rows [wv*32, wv*32+32) x the block's 64 columns.
// ---------------------------------------------------------------------------
__global__ __launch_bounds__(1024, 4)
void arcface_main(const unsigned short* __restrict__ bfrag,
                  const unsigned short* __restrict__ afrag,
                  const float* __restrict__ rnorm,
                  const int* __restrict__ labels,
                  float* __restrict__ out) {
  __shared__ alignas(16) unsigned short B2[2][2048];   // 2 x 4 KB B step-frags
  __shared__ float red[16][BC];
  __shared__ float colv[BC];

  const int tid = threadIdx.x;
  const int wv  = tid >> 6;        // 0..15
  const int l   = tid & 63;
  const int lh  = l >> 4;
  const int ll  = l & 15;
  const int c0  = blockIdx.x * BC;
  const int cb0 = blockIdx.x * 2;  // first 32-col group of this block

  const char* bfb  = (const char*)bfrag;
  const char* aptr = (const char*)afrag + (size_t)(wv * 2) * 1024 + (size_t)l * 16;
  char* b2b = (char*)&B2[0][0];

  f32x4 acc[2][4] = {};
  bf16x8 a2[2][2];

  // stage B frags for step KS into buffer BUF (4 x 1 KB, waves 0-3)
#define STAGE(KS, BUF)                                                          \
  if (wv < 4) {                                                                 \
    const int dof = __builtin_amdgcn_readfirstlane((BUF) * 4096 + wv * 1024);   \
    __builtin_amdgcn_global_load_lds(                                           \
        (const __attribute__((address_space(1))) void*)                        \
            (bfb + (size_t)((cb0 + (wv >> 1)) * 32 + (KS) * 2 + (wv & 1)) * 1024 \
                 + (size_t)l * 16),                                             \
        (__attribute__((address_space(3))) void*)(b2b + dof), 16, 0, 0);        \
  }

  // prologue (stager queue: B0, A0 x2, B1 -> step0 wait vmcnt(1) keeps B1 flying)
  STAGE(0, 0)
  a2[0][0] = *reinterpret_cast<const bf16x8*>(aptr + 0);
  a2[0][1] = *reinterpret_cast<const bf16x8*>(aptr + 1024);
  STAGE(1, 1)

  // Per step K: wait A(K)+B(K) landed (counted: B(K+1) stays in flight) -> barrier ->
  // ds_read B x4 -> issue A(K+1) direct -> lgkm(0) -> barrier (buf free) ->
  // stage B(K+2) -> MFMA x8.  Steady stager queue at wait: [A(K)x2 done, B(K+1)].
#define STEP(KS, VMS)                                                           \
  {                                                                             \
    if (wv < 4) { asm volatile("s_waitcnt vmcnt(" #VMS ")" ::: "memory"); }     \
    else        { asm volatile("s_waitcnt vmcnt(0)" ::: "memory"); }            \
    __builtin_amdgcn_s_barrier();                                               \
    __builtin_amdgcn_sched_barrier(0);                                          \
    bf16x8 b0 = *reinterpret_cast<const bf16x8*>(b2b + ((KS) & 1) * 4096 + 0 * 1024 + l * 16); \
    bf16x8 b1 = *reinterpret_cast<const bf16x8*>(b2b + ((KS) & 1) * 4096 + 1 * 1024 + l * 16); \
    bf16x8 b2 = *reinterpret_cast<const bf16x8*>(b2b + ((KS) & 1) * 4096 + 2 * 1024 + l * 16); \
    bf16x8 b3 = *reinterpret_cast<const bf16x8*>(b2b + ((KS) & 1) * 4096 + 3 * 1024 + l * 16); \
    if ((KS) + 1 < NSTEP) {                                                     \
      a2[((KS) + 1) & 1][0] =                                                   \
          *reinterpret_cast<const bf16x8*>(aptr + (size_t)((KS) + 1) * 32768);  \
      a2[((KS) + 1) & 1][1] =                                                   \
          *reinterpret_cast<const bf16x8*>(aptr + (size_t)((KS) + 1) * 32768 + 1024); \
    }                                                                           \
    asm volatile("s_waitcnt lgkmcnt(0)" ::: "memory");                          \
    __builtin_amdgcn_sched_barrier(0);                                          \
    __builtin_amdgcn_s_barrier();                                               \
    if ((KS) + 2 < NSTEP) STAGE((KS) + 2, (KS) & 1)                             \
    __builtin_amdgcn_sched_barrier(0);                                          \
    acc[0][0] = MFMA16(a2[(KS) & 1][0], b0, acc[0][0]);                         \
    acc[0][1] = MFMA16(a2[(KS) & 1][0], b1, acc[0][1]);                         \
    acc[0][2] = MFMA16(a2[(KS) & 1][0], b2, acc[0][2]);                         \
    acc[0][3] = MFMA16(a2[(KS) & 1][0], b3, acc[0][3]);                         \
    acc[1][0] = MFMA16(a2[(KS) & 1][1], b0, acc[1][0]);                         \
    acc[1][1] = MFMA16(a2[(KS) & 1][1], b1, acc[1][1]);                         \
    acc[1][2] = MFMA16(a2[(KS) & 1][1], b2, acc[1][2]);                         \
    acc[1][3] = MFMA16(a2[(KS) & 1][1], b3, acc[1][3]);                         \
  }

  STEP(0, 1)   STEP(1, 1)   STEP(2, 1)   STEP(3, 1)
  STEP(4, 1)   STEP(5, 1)   STEP(6, 1)   STEP(7, 1)
  STEP(8, 1)   STEP(9, 1)   STEP(10, 1)  STEP(11, 1)
  STEP(12, 1)  STEP(13, 1)  STEP(14, 1)  STEP(15, 0)
#undef STEP
#undef STAGE

  // ---- epilogue (fixed-shift softmax; labels are global col ids)
  float rn[4];
#pragma unroll
  for (int jj = 0; jj < 4; ++jj) rn[jj] = rnorm[c0 + jj * 16 + ll];

  int lab[2][4];
#pragma unroll
  for (int i = 0; i < 2; ++i)
#pragma unroll
    for (int q = 0; q < 4; ++q)
      lab[i][q] = labels[wv * 32 + i * 16 + lh * 4 + q];

  float sme[4] = {0.f, 0.f, 0.f, 0.f};
#pragma unroll
  for (int jj = 0; jj < 4; ++jj) {
    const int cj = c0 + jj * 16 + ll;
#pragma unroll
    for (int i = 0; i < 2; ++i) {
#pragma unroll
      for (int q = 0; q < 4; ++q) {
        float cosv = acc[i][jj][q] * rn[jj];
        cosv = fminf(fmaxf(cosv, -1.f), 1.f);
        float lg;
        if (lab[i][q] == cj) {
          const float s = sqrtf(fmaxf(1.f - cosv * cosv, 0.f));
          lg = cosv * COS_M - s * SIN_M;
        } else {
          lg = cosv;
        }
        const float e = __expf(lg * SCALE - SHIFT);
        acc[i][jj][q] = e;
        sme[jj] += e;
      }
    }
  }

  // column sums: within wave (rows differ by lh -> xor 16/32), then 16 waves via LDS
#pragma unroll
  for (int jj = 0; jj < 4; ++jj) {
    sme[jj] += __shfl_xor(sme[jj], 16, 64);
    sme[jj] += __shfl_xor(sme[jj], 32, 64);
  }
  if (l < 16) {
#pragma unroll
    for (int jj = 0; jj < 4; ++jj) red[wv][jj * 16 + l] = sme[jj];
  }
  __syncthreads();
  if (tid < BC) {
    float s = 0.f;
#pragma unroll
    for (int v2 = 0; v2 < 16; ++v2) s += red[v2][tid];
    colv[tid] = s;
  }
  __syncthreads();

#pragma unroll
  for (int jj = 0; jj < 4; ++jj) {
    const int cj = c0 + jj * 16 + ll;
    if (cj >= NCLS) continue;   // last block: cols 100000..100031 invalid
    const float rs = 1.0f / colv[jj * 16 + ll];
#pragma unroll
    for (int i = 0; i < 2; ++i) {
#pragma unroll
      for (int q = 0; q < 4; ++q) {
        const int row = wv * 32 + i * 16 + lh * 4 + q;
        out[(size_t)row * NCLS + cj] = acc[i][jj][q] * rs;
      }
    }
  }
}

extern "C" void kernel_launch(void* const* d_in, const int* in_sizes, int n_in,
                              void* d_out, int out_size, void* d_ws, size_t ws_size,
                              hipStream_t stream) {
  const float* emb = (const float*)d_in[0];   // [512][512]
  const float* w   = (const float*)d_in[1];   // [512][100000]
  const float* tgt = (const float*)d_in[2];   // [512][100000]
  float* out = (float*)d_out;                 // [512][100000]

  char* ws = (char*)d_ws;
  int* labels           = (int*)ws;                              // 2 KB
  unsigned short* afrag = (unsigned short*)(ws + 4096);          // 512 KB
  float* rnorm          = (float*)(ws + (1u << 20));             // 400 KB (padded)
  unsigned short* bfrag = (unsigned short*)(ws + (2u << 20));    // 100.03 MB (padded)

  label_scan<<<dim3(NROWS, 4), 1024, 0, stream>>>(tgt, labels);
  prep_afrag<<<64, 512, 0, stream>>>(emb, afrag);
  wt_kernel<<<WTBLK, 256, 0, stream>>>(w, bfrag, rnorm);
  arcface_main<<<NBLK, 1024, 0, stream>>>(bfrag, afrag, rnorm, labels, out);
}

// Round 14
// 268.974 us; speedup vs baseline: 1.1916x; 1.0203x over previous
//
#include <hip/hip_runtime.h>
#include <hip/hip_bf16.h>

// ArcFace fused: cos = emb @ (w/||w||), margin at target label, softmax over batch axis.
// N=512, D=512, C=100000 (= 3125*32 exact -> BC=32, zero guards), S=1.
//
// ROUND 14: r12/r13 validated counted-vmcnt LDS staging (250->159us) but ran ~1
// block/CU (4 waves/SIMD reg cap) -- nothing overlaps the per-step waits and the
// epilogue. This round shrinks to <=64 unified regs/lane (acc[2][2]=16 AGPR, A-ring
// 16, B 8) with launch_bounds(1024,8) -> 2 blocks/CU co-resident (target 32 waves).
// Triple-buffered B + ONE barrier per step (write-after-read safe: barrier(K) implies
// all waves passed their step K-1 lgkmcnt(0); stager's vmcnt(1) precedes the barrier
// so B(K)'s landing is visible to all readers).
//
//   label_scan : tgt one-hot -> labels[512]        (~35us, BW floor)
//   prep_afrag : emb f32 -> bf16 A-fragments       (512 KB, L2-resident)
//   wt_kernel  : w f32 -> bf16 B-fragments + rsqrt col norms (~55us)
//   arcface_main: 1024 thr = 16 waves, wave = 32 rows x 32 cols. Per step:
//     [stager vmcnt(1) | other vmcnt(0)] -> s_barrier -> ds_read B(K) x2 ->
//     issue A(K+1) direct (L2) -> lgkmcnt(0) -> stage B(K+2) via gl_lds -> MFMA x4.
//     Fixed-shift softmax epilogue (validated r9).

static constexpr int DIM    = 512;
static constexpr int NROWS  = 512;
static constexpr int NCLS   = 100000;
static constexpr int BC     = 32;
static constexpr int BK     = 32;
static constexpr int NSTEP  = DIM / BK;        // 16
static constexpr int MT     = NROWS / 16;      // 32
static constexpr int NBLK   = NCLS / BC;       // 3125 exact

static constexpr float COS_M = 0.87758256189037271611f;  // cos(0.5)
static constexpr float SIN_M = 0.47942553860420300027f;  // sin(0.5)
static constexpr float SCALE = 64.0f;
static constexpr float SHIFT = 20.0f;          // fixed softmax shift

typedef __attribute__((ext_vector_type(8))) short bf16x8;
typedef __attribute__((ext_vector_type(4))) float f32x4;

#define MFMA16(A, B, C) __builtin_amdgcn_mfma_f32_16x16x32_bf16((A), (B), (C), 0, 0, 0)

__device__ __forceinline__ unsigned short f2bf(float f) {
  union { float f; unsigned u; } v; v.f = f;
  unsigned u = v.u;
  return (unsigned short)((u + 0x7FFFu + ((u >> 16) & 1u)) >> 16);
}

// ---------------------------------------------------------------------------
__global__ __launch_bounds__(1024)
void label_scan(const float* __restrict__ tgt, int* __restrict__ labels) {
  const int row = blockIdx.x;
  const int nq = NCLS / 4;
  const int q0 = blockIdx.y * (nq / 4);
  const int q1 = (blockIdx.y == 3) ? nq : q0 + (nq / 4);
  const float4* rp = reinterpret_cast<const float4*>(tgt + (size_t)row * NCLS);
  int found = -1;
  for (int c4 = q0 + threadIdx.x; c4 < q1; c4 += 1024) {
    const float4 v = rp[c4];
    if (v.x > 0.5f) found = c4 * 4 + 0;
    if (v.y > 0.5f) found = c4 * 4 + 1;
    if (v.z > 0.5f) found = c4 * 4 + 2;
    if (v.w > 0.5f) found = c4 * 4 + 3;
  }
  if (found >= 0) labels[row] = found;   // exactly one writer per row
}

// ---------------------------------------------------------------------------
__global__ void prep_afrag(const float* __restrict__ emb,
                           unsigned short* __restrict__ afrag) {
  const int idx = blockIdx.x * blockDim.x + threadIdx.x;  // 0..32767
  const int l  = idx & 63;
  const int mt = (idx >> 6) & 31;
  const int ks = idx >> 11;
  const int row = mt * 16 + (l & 15);
  const int k0  = ks * 32 + (l >> 4) * 8;

  unsigned short t[8];
#pragma unroll
  for (int j = 0; j < 8; ++j) t[j] = f2bf(emb[row * DIM + k0 + j]);

  uint4 v;
  v.x = (unsigned)t[0] | ((unsigned)t[1] << 16);
  v.y = (unsigned)t[2] | ((unsigned)t[3] << 16);
  v.z = (unsigned)t[4] | ((unsigned)t[5] << 16);
  v.w = (unsigned)t[6] | ((unsigned)t[7] << 16);
  *reinterpret_cast<uint4*>(&afrag[(size_t)idx * 8]) = v;
}

// ---------------------------------------------------------------------------
__global__ __launch_bounds__(256)
void wt_kernel(const float* __restrict__ w,
               unsigned short* __restrict__ bfrag,
               float* __restrict__ rnorm) {
  __shared__ float S[32][33];
  __shared__ float NRM[32][32];

  const int t  = threadIdx.x;
  const int cb = blockIdx.x;
  const int c0 = cb * 32;

  const int rk = t >> 3;
  const int rc = (t & 7) * 4;

  float4 nrm4 = {0.f, 0.f, 0.f, 0.f};

  for (int p = 0; p < NSTEP; ++p) {
    const float4 v = *reinterpret_cast<const float4*>(
        w + (size_t)(p * BK + rk) * NCLS + c0 + rc);
    nrm4.x += v.x * v.x; nrm4.y += v.y * v.y;
    nrm4.z += v.z * v.z; nrm4.w += v.w * v.w;
    __syncthreads();
    *reinterpret_cast<float4*>(&S[rk][rc]) = v;
    __syncthreads();

    if (t < 128) {
      const int l2 = t & 63;
      const int j  = t >> 6;
      const int col = j * 16 + (l2 & 15);
      const int kb  = (l2 >> 4) * 8;
      uint4 pk;
      pk.x = (unsigned)f2bf(S[kb + 0][col]) | ((unsigned)f2bf(S[kb + 1][col]) << 16);
      pk.y = (unsigned)f2bf(S[kb + 2][col]) | ((unsigned)f2bf(S[kb + 3][col]) << 16);
      pk.z = (unsigned)f2bf(S[kb + 4][col]) | ((unsigned)f2bf(S[kb + 5][col]) << 16);
      pk.w = (unsigned)f2bf(S[kb + 6][col]) | ((unsigned)f2bf(S[kb + 7][col]) << 16);
      *reinterpret_cast<uint4*>(
          &bfrag[(((size_t)(cb * NSTEP + p) * 2 + j) * 64 + l2) * 8]) = pk;
    }
  }

  NRM[rk][rc + 0] = nrm4.x;
  NRM[rk][rc + 1] = nrm4.y;
  NRM[rk][rc + 2] = nrm4.z;
  NRM[rk][rc + 3] = nrm4.w;
  __syncthreads();
  if (t < 32) {
    float s = 0.f;
#pragma unroll
    for (int g = 0; g < 32; ++g) s += NRM[g][t];
    rnorm[c0 + t] = rsqrtf(fmaxf(s, 1e-20f));
  }
}

// ---------------------------------------------------------------------------
// Main kernel. 1024 threads = 16 waves; wave wv owns rows [wv*32, wv*32+32)
// x the block's 32 columns. Target: 2 blocks/CU (<=64 unified regs).
// ---------------------------------------------------------------------------
__global__ __launch_bounds__(1024, 8)
void arcface_main(const unsigned short* __restrict__ bfrag,
                  const unsigned short* __restrict__ afrag,
                  const float* __restrict__ rnorm,
                  const int* __restrict__ labels,
                  float* __restrict__ out) {
  __shared__ alignas(16) unsigned short B3[3][1024];   // 3 x 2 KB B step-frags
  __shared__ float red[16][BC];
  __shared__ float colv[BC];

  const int tid = threadIdx.x;
  const int wv  = tid >> 6;        // 0..15
  const int l   = tid & 63;
  const int lh  = l >> 4;
  const int ll  = l & 15;
  const int c0  = blockIdx.x * BC;

  const char* bfb  = (const char*)bfrag + (size_t)blockIdx.x * 32768;
  const char* aptr = (const char*)afrag + (size_t)(wv * 2) * 1024 + (size_t)l * 16;
  char* b3b = (char*)&B3[0][0];

  f32x4 acc[2][2] = {};
  bf16x8 a2[2][2];   // A ring: [step&1][mt-pair]

  // stage B frag pair for step KS into buffer BUF (2 x 1 KB, waves 0-1)
#define STAGE(KS, BUF)                                                          \
  if (wv < 2) {                                                                 \
    const int dof = __builtin_amdgcn_readfirstlane((BUF) * 2048 + wv * 1024);   \
    __builtin_amdgcn_global_load_lds(                                           \
        (const __attribute__((address_space(1))) void*)                        \
            (bfb + (size_t)((KS) * 2 + wv) * 1024 + (size_t)l * 16),            \
        (__attribute__((address_space(3))) void*)(b3b + dof), 16, 0, 0);        \
  }

  // prologue queue (stager): B0, A0 x2, B1  -> step-0 wait vmcnt(1) keeps B1 flying
  STAGE(0, 0)
  a2[0][0] = *reinterpret_cast<const bf16x8*>(aptr + 0);
  a2[0][1] = *reinterpret_cast<const bf16x8*>(aptr + 1024);
  STAGE(1, 1)

  // STEP(K): wait(A(K) landed; B(K) implied older) -> barrier -> ds_read B(K) ->
  // issue A(K+1) -> lgkm(0) -> stage B(K+2) into (K+2)%3 -> 4 MFMA.
#define STEP(KS, VMS)                                                           \
  {                                                                             \
    if (wv < 2) { asm volatile("s_waitcnt vmcnt(" #VMS ")" ::: "memory"); }     \
    else        { asm volatile("s_waitcnt vmcnt(0)" ::: "memory"); }            \
    __builtin_amdgcn_s_barrier();                                               \
    __builtin_amdgcn_sched_barrier(0);                                          \
    bf16x8 b0 = *reinterpret_cast<const bf16x8*>(b3b + ((KS) % 3) * 2048 + l * 16);        \
    bf16x8 b1 = *reinterpret_cast<const bf16x8*>(b3b + ((KS) % 3) * 2048 + 1024 + l * 16); \
    if ((KS) + 1 < NSTEP) {                                                     \
      a2[((KS) + 1) & 1][0] =                                                   \
          *reinterpret_cast<const bf16x8*>(aptr + (size_t)((KS) + 1) * 32768);  \
      a2[((KS) + 1) & 1][1] =                                                   \
          *reinterpret_cast<const bf16x8*>(aptr + (size_t)((KS) + 1) * 32768 + 1024); \
    }                                                                           \
    asm volatile("s_waitcnt lgkmcnt(0)" ::: "memory");                          \
    __builtin_amdgcn_sched_barrier(0);                                          \
    if ((KS) + 2 < NSTEP) STAGE((KS) + 2, ((KS) + 2) % 3)                       \
    acc[0][0] = MFMA16(a2[(KS) & 1][0], b0, acc[0][0]);                         \
    acc[0][1] = MFMA16(a2[(KS) & 1][0], b1, acc[0][1]);                         \
    acc[1][0] = MFMA16(a2[(KS) & 1][1], b0, acc[1][0]);                         \
    acc[1][1] = MFMA16(a2[(KS) & 1][1], b1, acc[1][1]);                         \
  }

  STEP(0, 1)   STEP(1, 1)   STEP(2, 1)   STEP(3, 1)
  STEP(4, 1)   STEP(5, 1)   STEP(6, 1)   STEP(7, 1)
  STEP(8, 1)   STEP(9, 1)   STEP(10, 1)  STEP(11, 1)
  STEP(12, 1)  STEP(13, 1)  STEP(14, 1)  STEP(15, 0)
#undef STEP
#undef STAGE

  // ---- epilogue (fixed-shift softmax; labels are global col ids)
  float rn[2];
#pragma unroll
  for (int j = 0; j < 2; ++j) rn[j] = rnorm[c0 + j * 16 + ll];

  int lab[2][4];
#pragma unroll
  for (int i = 0; i < 2; ++i)
#pragma unroll
    for (int q = 0; q < 4; ++q)
      lab[i][q] = labels[wv * 32 + i * 16 + lh * 4 + q];

  float sme[2] = {0.f, 0.f};
#pragma unroll
  for (int j = 0; j < 2; ++j) {
    const int cj = c0 + j * 16 + ll;
#pragma unroll
    for (int i = 0; i < 2; ++i) {
#pragma unroll
      for (int q = 0; q < 4; ++q) {
        float cosv = acc[i][j][q] * rn[j];
        cosv = fminf(fmaxf(cosv, -1.f), 1.f);
        float lg;
        if (lab[i][q] == cj) {
          const float s = sqrtf(fmaxf(1.f - cosv * cosv, 0.f));
          lg = cosv * COS_M - s * SIN_M;
        } else {
          lg = cosv;
        }
        const float e = __expf(lg * SCALE - SHIFT);
        acc[i][j][q] = e;
        sme[j] += e;
      }
    }
  }

  // column sums: lanes sharing a column differ in lh (xor 16/32), then 16 waves
#pragma unroll
  for (int j = 0; j < 2; ++j) {
    sme[j] += __shfl_xor(sme[j], 16, 64);
    sme[j] += __shfl_xor(sme[j], 32, 64);
  }
  __syncthreads();   // K-loop LDS quiesced before red reuse is not needed (separate arrays), but red needs all waves
  if (l < 16) {
#pragma unroll
    for (int j = 0; j < 2; ++j) red[wv][j * 16 + l] = sme[j];
  }
  __syncthreads();
  if (tid < BC) {
    float s = 0.f;
#pragma unroll
    for (int v2 = 0; v2 < 16; ++v2) s += red[v2][tid];
    colv[tid] = s;
  }
  __syncthreads();

  float rs[2];
#pragma unroll
  for (int j = 0; j < 2; ++j) rs[j] = 1.0f / colv[j * 16 + ll];

#pragma unroll
  for (int j = 0; j < 2; ++j) {
    const int cj = c0 + j * 16 + ll;
#pragma unroll
    for (int i = 0; i < 2; ++i) {
#pragma unroll
      for (int q = 0; q < 4; ++q) {
        const int row = wv * 32 + i * 16 + lh * 4 + q;
        out[(size_t)row * NCLS + cj] = acc[i][j][q] * rs[j];
      }
    }
  }
}

extern "C" void kernel_launch(void* const* d_in, const int* in_sizes, int n_in,
                              void* d_out, int out_size, void* d_ws, size_t ws_size,
                              hipStream_t stream) {
  const float* emb = (const float*)d_in[0];   // [512][512]
  const float* w   = (const float*)d_in[1];   // [512][100000]
  const float* tgt = (const float*)d_in[2];   // [512][100000]
  float* out = (float*)d_out;                 // [512][100000]

  char* ws = (char*)d_ws;
  int* labels           = (int*)ws;                              // 2 KB
  unsigned short* afrag = (unsigned short*)(ws + 4096);          // 512 KB
  float* rnorm          = (float*)(ws + (1u << 20));             // 400 KB
  unsigned short* bfrag = (unsigned short*)(ws + (2u << 20));    // 100 MB

  label_scan<<<dim3(NROWS, 4), 1024, 0, stream>>>(tgt, labels);
  prep_afrag<<<64, 512, 0, stream>>>(emb, afrag);
  wt_kernel<<<NBLK, 256, 0, stream>>>(w, bfrag, rnorm);
  arcface_main<<<NBLK, 1024, 0, stream>>>(bfrag, afrag, rnorm, labels, out);
}